// Round 15
// baseline (53.977 us; speedup 1.0000x reference)
//
#include <hip/hip_runtime.h>

// ---------------------------------------------------------------------------
// LMU fused cell on MI355X (gfx950).  Round 15: coalesced chunk-major A-pack.
//   new_h = sigmoid([x|h|m] @ [Wx|Wh|Wm@AT]^T + u*(Wm@BT)^T)
//   new_m = m @ AT^T + u*BT^T     u = [x|h|m].e  (f32 exact, in prep)
// K0 lmu_pre (512 thr): [wpack 769 blks | wm2 128 blks | prep 512 blks].
//   prep: 32-row tile -> LDS (XOR-swizzled bf16) -> apack [112][16384][8]
//   chunk-major, all global accesses coalesced; u f32-exact.
// K1 lmu_gemm: R13 structure verbatim; only the A-stage address changed to
//   the chunk-major layout (consecutive lanes -> consecutive rows -> 1KB
//   contiguous per wave).  LDS layouts and mma identical to R13.
// ---------------------------------------------------------------------------

typedef __bf16 bf16;
typedef bf16  bf16x4 __attribute__((ext_vector_type(4)));
typedef bf16  bf16x8 __attribute__((ext_vector_type(8)));
typedef float f32x4  __attribute__((ext_vector_type(4)));
typedef unsigned short u16;

#define BATCH 16384
// ws offsets (u16 units)
#define WPACK 0            // [896/8][512][8] = 458752  (kk>=80 = Wm@AT)
#define ATPACK 458752      // [256/8][256][8] = 65536
#define WUOFF 524288       // 512 f32  (1024 u16)
#define UOFF  525312       // 16384 f32 (32768 u16)
#define APACK 558080       // [112][16384][8] u16 (chunk-major)
// end: 15,238,144 u16 = ~30.5 MB

#define PACK_ITEMS 393728      // 327680 + 65536 + 512 = 769*512
#define PACKA_BLOCKS 769
#define WM2_BLOCKS 128
#define PREP_BLOCKS 512        // 32 rows each

__device__ __forceinline__ u16 f2bf(float f) {
  unsigned u = __builtin_bit_cast(unsigned, f);
  u += 0x7FFFu + ((u >> 16) & 1u);   // RNE
  return (u16)(u >> 16);
}

__device__ __forceinline__ void gload16(const u16* g, u16* l) {
  __builtin_amdgcn_global_load_lds(
      (const __attribute__((address_space(1))) unsigned int*)g,
      (__attribute__((address_space(3))) unsigned int*)l, 16, 0, 0);
}

// ---------------- K0: merged prologue ---------------------------------------
__global__ __launch_bounds__(512) void lmu_pre(
    const float* __restrict__ Wx, const float* __restrict__ Wh,
    const float* __restrict__ Wm, const float* __restrict__ AT,
    const float* __restrict__ BT, const float* __restrict__ x,
    const float* __restrict__ h, const float* __restrict__ m,
    const float* __restrict__ ex, const float* __restrict__ eh,
    const float* __restrict__ em, u16* __restrict__ ws) {
  __shared__ __align__(16) char psm[57344];
  const int bx = blockIdx.x;
  const int t  = threadIdx.x;
  if (bx < PACKA_BLOCKS) {
    int i = bx * 512 + t;
    if (i < 327680) {                     // Wall^T[k][n], k<640
      int j = i & 7, rest = i >> 3;
      int n = rest & 511, kk = rest >> 9;
      int k = kk * 8 + j;
      float v = (k < 128) ? Wx[n * 128 + k] : Wh[n * 512 + (k - 128)];
      ws[WPACK + i] = f2bf(v);
    } else if (i < 393216) {              // atpack[kk][d][j] = AT[d][kk*8+j]
      int tt = i - 327680;
      int j = tt & 7, rest = tt >> 3;
      int d = rest & 255, kk = rest >> 8;
      ws[ATPACK + tt] = f2bf(AT[d * 256 + kk * 8 + j]);
    } else {                              // wu[n] = dot(Wm[n,:], BT)
      int n = i - 393216;
      float s = 0.f;
      for (int k = 0; k < 256; k += 4) {
        float4 wv = *(const float4*)(Wm + (size_t)n * 256 + k);
        float4 bv = *(const float4*)(BT + k);
        s += wv.x * bv.x + wv.y * bv.y + wv.z * bv.z + wv.w * bv.w;
      }
      ((float*)(ws + WUOFF))[n] = s;
    }
  } else if (bx < PACKA_BLOCKS + WM2_BLOCKS) {   // Wm2 = Wm @ AT
    float* wmt = (float*)psm;                    // 16x256 f32 = 16KB
    const int wq = bx - PACKA_BLOCKS;
    const int nb = (wq & 31) * 16, db = (wq >> 5) * 64;
#pragma unroll
    for (int it = 0; it < 2; ++it) {
      int f = it * 512 + t;                      // 1024 float4
      float4 v = *(const float4*)(Wm + (size_t)(nb + (f >> 6)) * 256 + (f & 63) * 4);
      *(float4*)(wmt + (f >> 6) * 256 + (f & 63) * 4) = v;
    }
    __syncthreads();
    const int d = db + (t & 63);
    const int nn = (t >> 6) * 2;                 // 2 rows per thread-group
    float acc[2] = {0.f, 0.f};
    for (int k = 0; k < 256; ++k) {
      float atv = AT[(size_t)k * 256 + d];
#pragma unroll
      for (int i2 = 0; i2 < 2; ++i2) acc[i2] += wmt[(nn + i2) * 256 + k] * atv;
    }
    const int kk = 80 + (d >> 3), j = d & 7;
#pragma unroll
    for (int i2 = 0; i2 < 2; ++i2)
      ws[WPACK + ((size_t)kk * 512 + (nb + nn + i2)) * 8 + j] = f2bf(acc[i2]);
  } else {                                       // prep: 32-row tile
    const int px   = bx - PACKA_BLOCKS - WM2_BLOCKS;   // 0..511
    const int lane = t & 63;
    const int wv   = t >> 6;                     // wave 0..7
    float* uo = (float*)(ws + UOFF);
    u16* ap = ws + APACK;
    // phase 1: f32 -> bf16 swizzled LDS rows + u dots (coalesced reads)
#pragma unroll
    for (int rr = 0; rr < 4; ++rr) {
      const int rl = wv * 4 + rr;                // 0..31
      const size_t rg = (size_t)px * 32 + rl;
      float s = 0.f;
#pragma unroll
      for (int j = 0; j < 4; ++j) {
        int slot = j * 64 + lane;
        if (slot < 224) {
          float4 a, e;
          if (slot < 32)       { int c = slot * 4;
            a = *(const float4*)(x + rg * 128 + c); e = *(const float4*)(ex + c); }
          else if (slot < 160) { int c = (slot - 32) * 4;
            a = *(const float4*)(h + rg * 512 + c); e = *(const float4*)(eh + c); }
          else                 { int c = (slot - 160) * 4;
            a = *(const float4*)(m + rg * 256 + c); e = *(const float4*)(em + c); }
          s += a.x * e.x + a.y * e.y + a.z * e.z + a.w * e.w;
          bf16x4 p = {(bf16)a.x, (bf16)a.y, (bf16)a.z, (bf16)a.w};
          int kk = slot >> 1, hf = slot & 1;
          *(bf16x4*)(psm + rl * 1792 + ((kk ^ (rl & 7)) << 4) + hf * 8) = p;
        }
      }
#pragma unroll
      for (int d = 1; d < 64; d <<= 1) s += __shfl_xor(s, d);
      if (lane == 0) uo[rg] = s;
    }
    __syncthreads();
    // phase 2: LDS -> chunk-major apack (coalesced writes)
#pragma unroll
    for (int it = 0; it < 7; ++it) {
      int flat = it * 512 + t;                   // 0..3583 = 112kk x 32r
      int kk = flat >> 5, r = flat & 31;
      bf16x8 v = *(const bf16x8*)(psm + r * 1792 + ((kk ^ (r & 7)) << 4));
      *(bf16x8*)(ap + ((size_t)kk * BATCH + (size_t)px * 32 + r) * 8) = v;
    }
  }
}

// ---------------- K1: main GEMM (R13 structure, coalesced A) ----------------
// grid 512 = 128 M-tiles x 4 N-slices; 512 thr; LDS 80KB (2 x 40KB dbuf).
// per 40KB buffer: A [8kb][128r][8] @0, B [8kk][128n][8] @8192 u16,
//                  S [8kk][64n][8] @16384 u16 (staged only for c>=10).
__global__ __launch_bounds__(512, 4) void lmu_gemm(
    const u16* __restrict__ ws, const float* __restrict__ BT,
    float* __restrict__ out) {
  __shared__ __align__(16) u16 smem[2 * 20480];
  const int tid  = threadIdx.x;
  const int lane = tid & 63;
  const int w    = tid >> 6;     // 0..7
  const int wr   = w >> 1;       // 0..3 (32-row slice)
  const int wc   = w & 1;        // 0..1 (64-col slice)
  const int lm   = lane & 15;
  const int kg   = lane >> 4;
  const int bid  = blockIdx.x;
  const int mi   = (bid & 7) | ((bid >> 5) << 3);  // same-M N-slices -> same XCD
  const int nsl  = (bid >> 3) & 3;
  const int b0   = mi * 128;

  const u16* apack = ws + APACK;
  const u16* wpk   = ws + WPACK;
  const u16* atp   = ws + ATPACK;

  f32x4 acc[2][4];    // new_h: 2 Mfrag x 4 Nfrag (32r x 64c per wave)
  f32x4 acc2[2][2];   // new_m: 2 Mfrag x 2 Nfrag (32c per wave)
#pragma unroll
  for (int mt = 0; mt < 2; ++mt) {
#pragma unroll
    for (int ct = 0; ct < 4; ++ct) acc[mt][ct] = (f32x4){0.f, 0.f, 0.f, 0.f};
#pragma unroll
    for (int ct = 0; ct < 2; ++ct) acc2[mt][ct] = (f32x4){0.f, 0.f, 0.f, 0.f};
  }

  auto stage = [&](int c) {
    u16* buf = smem + (c & 1) * 20480;
#pragma unroll
    for (int ph = 0; ph < 2; ++ph) {           // A chunk: 16KB, COALESCED
      int i = ph * 512 + tid;
      int kb = i >> 7, r = i & 127;
      gload16(apack + ((size_t)(c * 8 + kb) * BATCH + b0 + r) * 8, buf + i * 8);
    }
#pragma unroll
    for (int ph = 0; ph < 2; ++ph) {           // B chunk: 16KB
      int i = ph * 512 + tid;
      int kk = i >> 7, n = i & 127;
      gload16(wpk + ((size_t)(c * 8 + kk) * 512 + nsl * 128 + n) * 8,
              buf + 8192 + i * 8);
    }
    if (c >= 10) {                              // side B (atpack): 8KB
      int kk = tid >> 6, n = tid & 63;
      gload16(atp + ((size_t)((c - 10) * 8 + kk) * 256 + nsl * 64 + n) * 8,
              buf + 16384 + tid * 8);
    }
  };

  auto mma = [&](int c) {
    const u16* buf = smem + (c & 1) * 20480;
#pragma unroll
    for (int ks = 0; ks < 2; ++ks) {
      const int kq = ks * 4 + kg;
      bf16x8 a[2];
#pragma unroll
      for (int mt = 0; mt < 2; ++mt)
        a[mt] = *(const bf16x8*)(buf + (kq * 128 + wr * 32 + mt * 16 + lm) * 8);
#pragma unroll
      for (int ct = 0; ct < 4; ++ct) {
        bf16x8 b = *(const bf16x8*)(buf + 8192 + (kq * 128 + wc * 64 + ct * 16 + lm) * 8);
#pragma unroll
        for (int mt = 0; mt < 2; ++mt)
          acc[mt][ct] = __builtin_amdgcn_mfma_f32_16x16x32_bf16(a[mt], b, acc[mt][ct], 0, 0, 0);
      }
      if (c >= 10) {
#pragma unroll
        for (int ct = 0; ct < 2; ++ct) {
          bf16x8 b = *(const bf16x8*)(buf + 16384 + (kq * 64 + wc * 32 + ct * 16 + lm) * 8);
#pragma unroll
          for (int mt = 0; mt < 2; ++mt)
            acc2[mt][ct] = __builtin_amdgcn_mfma_f32_16x16x32_bf16(a[mt], b, acc2[mt][ct], 0, 0, 0);
        }
      }
    }
  };

  stage(0);
  __syncthreads();
#pragma unroll
  for (int c = 0; c < 14; ++c) {
    if (c < 13) stage(c + 1);   // issue next-chunk loads first (overlap)
    mma(c);                     // compute current from LDS
    __syncthreads();            // drains vmcnt -> next buffer ready
  }

  // ---- epilogue ----
  const float* uf  = (const float*)(ws + UOFF);
  const float* wuf = (const float*)(ws + WUOFF);
  float wuv[4], btv[2];
#pragma unroll
  for (int ct = 0; ct < 4; ++ct) wuv[ct] = wuf[nsl * 128 + wc * 64 + ct * 16 + lm];
#pragma unroll
  for (int ct = 0; ct < 2; ++ct) btv[ct] = BT[nsl * 64 + wc * 32 + ct * 16 + lm];
  float* outm = out + (size_t)BATCH * 512;
#pragma unroll
  for (int mt = 0; mt < 2; ++mt)
#pragma unroll
    for (int j = 0; j < 4; ++j) {
      int rl = wr * 32 + mt * 16 + kg * 4 + j;
      size_t row = (size_t)(b0 + rl);
      float uv = uf[row];
#pragma unroll
      for (int ct = 0; ct < 4; ++ct) {
        float v = acc[mt][ct][j] + uv * wuv[ct];
        out[row * 512 + nsl * 128 + wc * 64 + ct * 16 + lm] = 1.0f / (1.0f + __expf(-v));
      }
#pragma unroll
      for (int ct = 0; ct < 2; ++ct)
        outm[row * 256 + nsl * 64 + wc * 32 + ct * 16 + lm] = acc2[mt][ct][j] + uv * btv[ct];
    }
}

extern "C" void kernel_launch(void* const* d_in, const int* in_sizes, int n_in,
                              void* d_out, int out_size, void* d_ws, size_t ws_size,
                              hipStream_t stream) {
  const float* x  = (const float*)d_in[0];
  const float* h  = (const float*)d_in[1];
  const float* m  = (const float*)d_in[2];
  const float* Wx = (const float*)d_in[3];
  const float* Wh = (const float*)d_in[4];
  const float* Wm = (const float*)d_in[5];
  const float* ex = (const float*)d_in[6];
  const float* eh = (const float*)d_in[7];
  const float* em = (const float*)d_in[8];
  const float* AT = (const float*)d_in[9];
  const float* BT = (const float*)d_in[10];
  float* out = (float*)d_out;
  u16* ws = (u16*)d_ws;   // uses ~30.5 MB

  lmu_pre<<<PACKA_BLOCKS + WM2_BLOCKS + PREP_BLOCKS, 512, 0, stream>>>(
      Wx, Wh, Wm, AT, BT, x, h, m, ex, eh, em, ws);
  lmu_gemm<<<512, 512, 0, stream>>>(ws, BT, out);
}